// Round 2
// baseline (268.453 us; speedup 1.0000x reference)
//
#include <hip/hip_runtime.h>
#include <hip/hip_bf16.h>

#define V     8192
#define E_N   262144
#define NN    262144
#define D     128
#define KDIM  8192

typedef __attribute__((ext_vector_type(8))) short b16x8;
typedef __attribute__((ext_vector_type(4))) float f32x4;

static __device__ __forceinline__ unsigned short f2bf(float f) {
    union { float f; unsigned int u; } v; v.f = f;
    unsigned int r = v.u + 0x7FFFu + ((v.u >> 16) & 1u);   // RNE
    return (unsigned short)(r >> 16);
}

static __device__ __forceinline__ unsigned int cvtpk(float lo, float hi) {
    unsigned int r;
    asm("v_cvt_pk_bf16_f32 %0, %1, %2" : "=v"(r) : "v"(lo), "v"(hi));
    return r;
}

// ---- W [K][D] fp32 -> WbT [D][K] bf16 (transposed, linear) ----
__global__ void k_wbt(const float* __restrict__ W, unsigned short* __restrict__ WbT) {
    __shared__ float tile[32][33];
    int bk = blockIdx.x & 255;      // K/32
    int bn = blockIdx.x >> 8;       // D/32
    int r = threadIdx.x >> 5;       // 0..7
    int c = threadIdx.x & 31;
    int k0 = bk * 32, n0 = bn * 32;
    for (int i = 0; i < 4; i++)
        tile[r + 8 * i][c] = W[(size_t)(k0 + r + 8 * i) * D + n0 + c];
    __syncthreads();
    for (int i = 0; i < 4; i++)
        WbT[(size_t)(n0 + r + 8 * i) * KDIM + k0 + c] = f2bf(tile[c][r + 8 * i]);
}

// ---- H := broadcast(b) ----
__global__ void k_initH(float* __restrict__ H, const float* __restrict__ b) {
    int t = blockIdx.x * 256 + threadIdx.x;
    H[t] = b[t & (D - 1)];
}

// ---- degree histogram over dst ----
__global__ void k_hist(const int* __restrict__ dst, int* __restrict__ hist) {
    int e = blockIdx.x * 256 + threadIdx.x;
    if (e < E_N) atomicAdd(&hist[dst[e]], 1);
}

// ---- exclusive scan of 8192 counts, single block ----
__global__ void k_scan(const int* __restrict__ hist, int* __restrict__ offsets,
                       int* __restrict__ cursor) {
    __shared__ int part[1024];
    int t = threadIdx.x;
    int base = t * 8;
    int loc[8]; int s = 0;
    for (int i = 0; i < 8; i++) { loc[i] = s; s += hist[base + i]; }
    part[t] = s;
    __syncthreads();
    for (int st = 1; st < 1024; st <<= 1) {
        int v = (t >= st) ? part[t - st] : 0;
        __syncthreads();
        part[t] += v;
        __syncthreads();
    }
    int ex = (t == 0) ? 0 : part[t - 1];
    for (int i = 0; i < 8; i++) {
        int o = ex + loc[i];
        offsets[base + i] = o;
        cursor[base + i] = o;
    }
    if (t == 1023) offsets[8192] = ex + s;
}

// ---- scatter edges into CSR-by-dst ----
__global__ void k_scatter(const int* __restrict__ srcI, const int* __restrict__ dstI,
                          const float* __restrict__ w, int* __restrict__ cursor,
                          int* __restrict__ src_s, float* __restrict__ w_s) {
    int e = blockIdx.x * 256 + threadIdx.x;
    if (e < E_N) {
        int dnode = dstI[e];
        int pos = atomicAdd(&cursor[dnode], 1);
        src_s[pos] = srcI[e];
        w_s[pos]  = w[e];
    }
}

// ---- H += A@W : barrier-free, global_load_lds A-stream, B direct from L2 ----
// grid = 128 row-blocks x 8 splitK; block = 256 thr = 4 waves, 4M x 1N.
// Wave w owns A rows rb*64 + w*16 .. +16 exclusively -> per-wave vmcnt only.
__global__ void __launch_bounds__(256) k_gemm(const float* __restrict__ A,
                                              const unsigned short* __restrict__ WbT,
                                              float* __restrict__ H) {
    __shared__ float Asl[2][64][32];      // 16 KB, double-buffered BK=32 fp32 tile

    const int rb   = blockIdx.x >> 3;     // 0..127
    const int ks   = blockIdx.x & 7;      // K slice of 1024
    const int tid  = threadIdx.x;
    const int w    = tid >> 6;            // wave 0..3
    const int lane = tid & 63;
    const int r16  = lane & 15;
    const int kg   = lane >> 4;           // 0..3

    // staging: instr j in {0,1}: lane covers row w*16 + j*8 + lane/8, 16B at col (lane%8)*4
    const float* aSrc0 = A + (size_t)(rb * 64 + w * 16 + (lane >> 3)) * KDIM
                           + ks * 1024 + (lane & 7) * 4;
    const float* aSrc1 = aSrc0 + (size_t)8 * KDIM;

    const unsigned short* bBase = WbT + (size_t)r16 * KDIM + ks * 1024 + kg * 8;

    f32x4 acc[8];
    f32x4 zero = {0.f, 0.f, 0.f, 0.f};
    #pragma unroll
    for (int t = 0; t < 8; t++) acc[t] = zero;

#define STAGE(nk, nb)                                                                  \
    do {                                                                               \
        __builtin_amdgcn_global_load_lds(                                              \
            (const __attribute__((address_space(1))) void*)(aSrc0 + (nk) * 32),        \
            (__attribute__((address_space(3))) void*)&Asl[nb][w * 16][0], 16, 0, 0);   \
        __builtin_amdgcn_global_load_lds(                                              \
            (const __attribute__((address_space(1))) void*)(aSrc1 + (nk) * 32),        \
            (__attribute__((address_space(3))) void*)&Asl[nb][w * 16 + 8][0], 16, 0, 0);\
    } while (0)

    STAGE(0, 0);                           // prologue: A(0) in flight

    for (int kt = 0; kt < 32; ++kt) {
        // B fragments for kt: 8 x 16B, L2-resident
        b16x8 bv[8];
        #pragma unroll
        for (int t = 0; t < 8; t++)
            bv[t] = *(const b16x8*)(bBase + (size_t)t * 16 * KDIM + kt * 32);

        // WAR guard: prior ds_reads of the buffer we're about to overwrite are done
        asm volatile("s_waitcnt lgkmcnt(0)" ::: "memory");
        const int nk = (kt + 1 < 32) ? kt + 1 : 31;   // last iter restages (harmless)
        STAGE(nk, (kt + 1) & 1);

        // queue: [A(kt):2][B(kt):8][A(kt+1):2] -> vmcnt(10) completes A(kt) only
        asm volatile("s_waitcnt vmcnt(10)" ::: "memory");

        const float* ap = &Asl[kt & 1][w * 16 + r16][kg * 8];
        f32x4 a0 = *(const f32x4*)ap;
        f32x4 a1 = *(const f32x4*)(ap + 4);
        union { b16x8 v; unsigned int u[4]; } af;
        af.u[0] = cvtpk(a0[0], a0[1]);
        af.u[1] = cvtpk(a0[2], a0[3]);
        af.u[2] = cvtpk(a1[0], a1[1]);
        af.u[3] = cvtpk(a1[2], a1[3]);

        #pragma unroll
        for (int t = 0; t < 8; t++)
            acc[t] = __builtin_amdgcn_mfma_f32_16x16x32_bf16(af.v, bv[t], acc[t], 0, 0, 0);
    }
#undef STAGE

    // C/D map (16x16x32): col = lane&15, row = kg*4 + j
    const int rbase = rb * 64 + w * 16 + kg * 4;
    #pragma unroll
    for (int t = 0; t < 8; t++) {
        int col = t * 16 + r16;
        #pragma unroll
        for (int j = 0; j < 4; j++)
            atomicAdd(&H[(size_t)(rbase + j) * D + col], acc[t][j]);
    }
}

// ---- emb = 0.8*P + 0.2*H, L2-normalize per row (V rows) ----
__global__ void k_emb(const float* __restrict__ H, const int* __restrict__ offsets,
                      const int* __restrict__ src_s, const float* __restrict__ w_s,
                      float* __restrict__ embn) {
    __shared__ float red[128];
    int v = blockIdx.x;
    int d = threadIdx.x;
    int s0 = offsets[v], s1 = offsets[v + 1];
    float acc = 0.f;
    for (int i = s0; i < s1; i++) {
        int s = src_s[i];
        float w = w_s[i];
        acc = fmaf(w, H[(size_t)s * D + d], acc);
    }
    float e = 0.8f * acc + 0.2f * H[(size_t)v * D + d];
    red[d] = e * e;
    __syncthreads();
    for (int st = 64; st > 0; st >>= 1) {
        if (d < st) red[d] += red[d + st];
        __syncthreads();
    }
    float norm = sqrtf(red[0]);
    float scale = 1.f / fmaxf(norm, 1e-12f);
    embn[(size_t)v * D + d] = e * scale;
}

// ---- out[n] = embn[x[n]] ----
__global__ void k_out(const int* __restrict__ x, const float* __restrict__ embn,
                      float* __restrict__ out) {
    int t = blockIdx.x * 256 + threadIdx.x;   // over NN * 32
    int n = t >> 5, c = t & 31;
    int xv = x[n];
    ((f32x4*)out)[t] = ((const f32x4*)embn)[xv * 32 + c];
}

extern "C" void kernel_launch(void* const* d_in, const int* in_sizes, int n_in,
                              void* d_out, int out_size, void* d_ws, size_t ws_size,
                              hipStream_t stream) {
    const int*   x      = (const int*)d_in[0];
    const int*   eSrc   = (const int*)d_in[1];          // edge_index[0]
    const int*   eDst   = ((const int*)d_in[1]) + E_N;  // edge_index[1]
    const float* eW     = (const float*)d_in[2];
    const float* A      = (const float*)d_in[3];        // embedding [V][V]
    const float* W      = (const float*)d_in[4];        // [V][D]
    const float* b      = (const float*)d_in[5];        // [D]
    float* out = (float*)d_out;

    char* ws = (char*)d_ws;
    unsigned short* WbT = (unsigned short*)(ws);                       // 2 MB
    float* H            = (float*)(ws + (2u << 20));                   // 4 MB
    float* embn         = (float*)(ws + (6u << 20));                   // 4 MB
    int* offsets        = (int*)(ws + (10u << 20));                    // 8193 ints
    int* cursor         = (int*)(ws + (10u << 20) + 40960);            // 8192 ints (also hist)
    int* src_s          = (int*)(ws + (10u << 20) + 131072);           // 1 MB
    float* w_s          = (float*)(ws + (10u << 20) + 131072 + (1u << 20)); // 1 MB

    hipMemsetAsync(cursor, 0, V * sizeof(int), stream);
    k_wbt    <<<1024, 256, 0, stream>>>(W, WbT);
    k_initH  <<<(V * D) / 256, 256, 0, stream>>>(H, b);
    k_hist   <<<E_N / 256, 256, 0, stream>>>(eDst, cursor);
    k_scan   <<<1, 1024, 0, stream>>>(cursor, offsets, cursor);
    k_scatter<<<E_N / 256, 256, 0, stream>>>(eSrc, eDst, eW, cursor, src_s, w_s);
    k_gemm   <<<1024, 256, 0, stream>>>(A, WbT, H);
    k_emb    <<<V, D, 0, stream>>>(H, offsets, src_s, w_s, embn);
    k_out    <<<(NN * 32) / 256, 256, 0, stream>>>(x, embn, out);
}

// Round 3
// 227.338 us; speedup vs baseline: 1.1809x; 1.1809x over previous
//
#include <hip/hip_runtime.h>
#include <hip/hip_bf16.h>

#define V     8192
#define E_N   262144
#define NN    262144
#define D     128
#define KDIM  8192

typedef __attribute__((ext_vector_type(8))) short b16x8;
typedef __attribute__((ext_vector_type(4))) float f32x4;

static __device__ __forceinline__ unsigned short f2bf(float f) {
    union { float f; unsigned int u; } v; v.f = f;
    unsigned int r = v.u + 0x7FFFu + ((v.u >> 16) & 1u);   // RNE
    return (unsigned short)(r >> 16);
}

static __device__ __forceinline__ unsigned int cvtpk(float lo, float hi) {
    unsigned int r;
    asm("v_cvt_pk_bf16_f32 %0, %1, %2" : "=v"(r) : "v"(lo), "v"(hi));
    return r;
}

// ---- W [K][D] fp32 -> Wp[kb][c][kk] bf16 (K-major pack: kb=k>>5, kk=k&31) ----
// One block per kb; fully coalesced read and write; LDS transpose with +1 pad.
__global__ void k_pack(const float* __restrict__ W, unsigned short* __restrict__ Wp) {
    __shared__ float tile[32][129];
    int kb = blockIdx.x;            // 0..255
    int t  = threadIdx.x;           // 0..255
    #pragma unroll
    for (int i = 0; i < 16; i++) {
        int lin = i * 256 + t;      // 0..4095 over (kk,c)
        int kk = lin >> 7, c = lin & 127;
        tile[kk][c] = W[(size_t)(kb * 32 + kk) * D + c];
    }
    __syncthreads();
    unsigned short* outp = Wp + (size_t)kb * 4096;
    #pragma unroll
    for (int i = 0; i < 16; i++) {
        int o = i * 256 + t;        // 0..4095 over (c,kk)
        int c = o >> 5, kk = o & 31;
        outp[o] = f2bf(tile[kk][c]);
    }
}

// ---- H := broadcast(b) ----
__global__ void k_initH(float* __restrict__ H, const float* __restrict__ b) {
    int t = blockIdx.x * 256 + threadIdx.x;
    H[t] = b[t & (D - 1)];
}

// ---- degree histogram over dst ----
__global__ void k_hist(const int* __restrict__ dst, int* __restrict__ hist) {
    int e = blockIdx.x * 256 + threadIdx.x;
    if (e < E_N) atomicAdd(&hist[dst[e]], 1);
}

// ---- exclusive scan of 8192 counts, single block ----
__global__ void k_scan(const int* __restrict__ hist, int* __restrict__ offsets,
                       int* __restrict__ cursor) {
    __shared__ int part[1024];
    int t = threadIdx.x;
    int base = t * 8;
    int loc[8]; int s = 0;
    for (int i = 0; i < 8; i++) { loc[i] = s; s += hist[base + i]; }
    part[t] = s;
    __syncthreads();
    for (int st = 1; st < 1024; st <<= 1) {
        int v = (t >= st) ? part[t - st] : 0;
        __syncthreads();
        part[t] += v;
        __syncthreads();
    }
    int ex = (t == 0) ? 0 : part[t - 1];
    for (int i = 0; i < 8; i++) {
        int o = ex + loc[i];
        offsets[base + i] = o;
        cursor[base + i] = o;
    }
    if (t == 1023) offsets[8192] = ex + s;
}

// ---- scatter edges into CSR-by-dst ----
__global__ void k_scatter(const int* __restrict__ srcI, const int* __restrict__ dstI,
                          const float* __restrict__ w, int* __restrict__ cursor,
                          int* __restrict__ src_s, float* __restrict__ w_s) {
    int e = blockIdx.x * 256 + threadIdx.x;
    if (e < E_N) {
        int dnode = dstI[e];
        int pos = atomicAdd(&cursor[dnode], 1);
        src_s[pos] = srcI[e];
        w_s[pos]  = w[e];
    }
}

// ---- H += A@W : pure-register GEMM, no LDS, no barriers ----
// grid = 128 row-blocks x 8 splitK; block = 4 waves; wave = 16 rows x 128 cols.
// A fragments are lane-private -> direct global->VGPR f32x4 loads (no reuse lost).
// B from K-major pack Wp (L2-resident, 2 MB). 2-deep software pipeline with
// named register sets; compiler inserts precise vmcnt waits (no asm control).
__global__ void __launch_bounds__(256) k_gemm(const float* __restrict__ A,
                                              const unsigned short* __restrict__ Wp,
                                              float* __restrict__ H) {
    const int rb   = blockIdx.x >> 3;     // 0..127
    const int ks   = blockIdx.x & 7;      // K slice of 1024
    const int tid  = threadIdx.x;
    const int w    = tid >> 6;
    const int lane = tid & 63;
    const int r16  = lane & 15;
    const int kg   = lane >> 4;           // 0..3

    // A: row rb*64 + w*16 + r16, this lane's 8 floats at k = ks*1024 + kt*32 + kg*8
    const float* aP = A + (size_t)(rb * 64 + w * 16 + r16) * KDIM + ks * 1024 + kg * 8;
    // B: Wp[kb = ks*32 + kt][c = t*16 + r16][kk = kg*8]
    const unsigned short* bP = Wp + (size_t)(ks * 32) * 4096 + r16 * 32 + kg * 8;

    f32x4 acc[8];
    f32x4 zero = {0.f, 0.f, 0.f, 0.f};
    #pragma unroll
    for (int t = 0; t < 8; t++) acc[t] = zero;

#define ISSUE(aa0, aa1, bb, kt)                                        \
    do {                                                               \
        const float* ap_ = aP + (kt) * 32;                             \
        aa0 = *(const f32x4*)ap_;                                      \
        aa1 = *(const f32x4*)(ap_ + 4);                                \
        const b16x8* bp_ = (const b16x8*)(bP + (size_t)(kt) * 4096);   \
        _Pragma("unroll")                                              \
        for (int t = 0; t < 8; t++) bb[t] = bp_[t * 64];               \
    } while (0)

#define COMPUTE(aa0, aa1, bb)                                                          \
    do {                                                                               \
        union { b16x8 v; unsigned int u[4]; } af_;                                     \
        af_.u[0] = cvtpk(aa0[0], aa0[1]);                                              \
        af_.u[1] = cvtpk(aa0[2], aa0[3]);                                              \
        af_.u[2] = cvtpk(aa1[0], aa1[1]);                                              \
        af_.u[3] = cvtpk(aa1[2], aa1[3]);                                              \
        _Pragma("unroll")                                                              \
        for (int t = 0; t < 8; t++)                                                    \
            acc[t] = __builtin_amdgcn_mfma_f32_16x16x32_bf16(af_.v, bb[t], acc[t], 0, 0, 0); \
    } while (0)

    f32x4 a0A, a1A, a0B, a1B;
    b16x8 bA[8], bB[8];

    ISSUE(a0A, a1A, bA, 0);
    for (int kt = 0; kt < 32; kt += 2) {
        ISSUE(a0B, a1B, bB, kt + 1);
        COMPUTE(a0A, a1A, bA);
        ISSUE(a0A, a1A, bA, (kt + 2) & 31);   // wraps to 0 on last iter (harmless)
        COMPUTE(a0B, a1B, bB);
    }
#undef ISSUE
#undef COMPUTE

    // C/D map (16x16x32): col = lane&15, row = kg*4 + j
    const int rbase = rb * 64 + w * 16 + kg * 4;
    #pragma unroll
    for (int t = 0; t < 8; t++) {
        int col = t * 16 + r16;
        #pragma unroll
        for (int j = 0; j < 4; j++)
            atomicAdd(&H[(size_t)(rbase + j) * D + col], acc[t][j]);
    }
}

// ---- emb = 0.8*P + 0.2*H, L2-normalize per row (V rows) ----
__global__ void k_emb(const float* __restrict__ H, const int* __restrict__ offsets,
                      const int* __restrict__ src_s, const float* __restrict__ w_s,
                      float* __restrict__ embn) {
    __shared__ float red[128];
    int v = blockIdx.x;
    int d = threadIdx.x;
    int s0 = offsets[v], s1 = offsets[v + 1];
    float acc = 0.f;
    for (int i = s0; i < s1; i++) {
        int s = src_s[i];
        float w = w_s[i];
        acc = fmaf(w, H[(size_t)s * D + d], acc);
    }
    float e = 0.8f * acc + 0.2f * H[(size_t)v * D + d];
    red[d] = e * e;
    __syncthreads();
    for (int st = 64; st > 0; st >>= 1) {
        if (d < st) red[d] += red[d + st];
        __syncthreads();
    }
    float norm = sqrtf(red[0]);
    float scale = 1.f / fmaxf(norm, 1e-12f);
    embn[(size_t)v * D + d] = e * scale;
}

// ---- out[n] = embn[x[n]] ----
__global__ void k_out(const int* __restrict__ x, const float* __restrict__ embn,
                      float* __restrict__ out) {
    int t = blockIdx.x * 256 + threadIdx.x;   // over NN * 32
    int n = t >> 5, c = t & 31;
    int xv = x[n];
    ((f32x4*)out)[t] = ((const f32x4*)embn)[xv * 32 + c];
}

extern "C" void kernel_launch(void* const* d_in, const int* in_sizes, int n_in,
                              void* d_out, int out_size, void* d_ws, size_t ws_size,
                              hipStream_t stream) {
    const int*   x      = (const int*)d_in[0];
    const int*   eSrc   = (const int*)d_in[1];          // edge_index[0]
    const int*   eDst   = ((const int*)d_in[1]) + E_N;  // edge_index[1]
    const float* eW     = (const float*)d_in[2];
    const float* A      = (const float*)d_in[3];        // embedding [V][V]
    const float* W      = (const float*)d_in[4];        // [V][D]
    const float* b      = (const float*)d_in[5];        // [D]
    float* out = (float*)d_out;

    char* ws = (char*)d_ws;
    unsigned short* Wp  = (unsigned short*)(ws);                       // 2 MB
    float* H            = (float*)(ws + (2u << 20));                   // 4 MB
    float* embn         = (float*)(ws + (6u << 20));                   // 4 MB
    int* offsets        = (int*)(ws + (10u << 20));                    // 8193 ints
    int* cursor         = (int*)(ws + (10u << 20) + 40960);            // 8192 ints (also hist)
    int* src_s          = (int*)(ws + (10u << 20) + 131072);           // 1 MB
    float* w_s          = (float*)(ws + (10u << 20) + 131072 + (1u << 20)); // 1 MB

    hipMemsetAsync(cursor, 0, V * sizeof(int), stream);
    k_pack   <<<256, 256, 0, stream>>>(W, Wp);
    k_initH  <<<(V * D) / 256, 256, 0, stream>>>(H, b);
    k_hist   <<<E_N / 256, 256, 0, stream>>>(eDst, cursor);
    k_scan   <<<1, 1024, 0, stream>>>(cursor, offsets, cursor);
    k_scatter<<<E_N / 256, 256, 0, stream>>>(eSrc, eDst, eW, cursor, src_s, w_s);
    k_gemm   <<<1024, 256, 0, stream>>>(A, Wp, H);
    k_emb    <<<V, D, 0, stream>>>(H, offsets, src_s, w_s, embn);
    k_out    <<<(NN * 32) / 256, 256, 0, stream>>>(x, embn, out);
}

// Round 4
// 219.552 us; speedup vs baseline: 1.2227x; 1.0355x over previous
//
#include <hip/hip_runtime.h>
#include <hip/hip_bf16.h>

#define V     8192
#define E_N   262144
#define NN    262144
#define D     128
#define KDIM  8192

typedef __attribute__((ext_vector_type(8))) short b16x8;
typedef __attribute__((ext_vector_type(4))) float f32x4;

static __device__ __forceinline__ unsigned short f2bf(float f) {
    union { float f; unsigned int u; } v; v.f = f;
    unsigned int r = v.u + 0x7FFFu + ((v.u >> 16) & 1u);   // RNE
    return (unsigned short)(r >> 16);
}

static __device__ __forceinline__ unsigned int cvtpk(float lo, float hi) {
    unsigned int r;
    asm("v_cvt_pk_bf16_f32 %0, %1, %2" : "=v"(r) : "v"(lo), "v"(hi));
    return r;
}

// ---- W [K][D] fp32 -> Wp[kb][c][kk] bf16 (kb=k>>5, kk=k&31); also zero cursor ----
__global__ void k_pack(const float* __restrict__ W, unsigned short* __restrict__ Wp,
                       int* __restrict__ cursor) {
    __shared__ float tile[32][129];
    int kb = blockIdx.x;            // 0..255
    int t  = threadIdx.x;           // 0..255
    if (kb < 32) cursor[kb * 256 + t] = 0;
    #pragma unroll
    for (int i = 0; i < 16; i++) {
        int lin = i * 256 + t;      // over (kk,c)
        int kk = lin >> 7, c = lin & 127;
        tile[kk][c] = W[(size_t)(kb * 32 + kk) * D + c];
    }
    __syncthreads();
    unsigned short* outp = Wp + (size_t)kb * 4096;
    #pragma unroll
    for (int i = 0; i < 16; i++) {
        int o = i * 256 + t;        // over (c,kk)
        int c = o >> 5, kk = o & 31;
        outp[o] = f2bf(tile[kk][c]);
    }
}

// ---- degree histogram over dst ----
__global__ void k_hist(const int* __restrict__ dst, int* __restrict__ hist) {
    int e = blockIdx.x * 256 + threadIdx.x;
    if (e < E_N) atomicAdd(&hist[dst[e]], 1);
}

// ---- exclusive scan of 8192 counts, single block ----
__global__ void k_scan(const int* __restrict__ hist, int* __restrict__ offsets,
                       int* __restrict__ cursor) {
    __shared__ int part[1024];
    int t = threadIdx.x;
    int base = t * 8;
    int loc[8]; int s = 0;
    for (int i = 0; i < 8; i++) { loc[i] = s; s += hist[base + i]; }
    part[t] = s;
    __syncthreads();
    for (int st = 1; st < 1024; st <<= 1) {
        int v = (t >= st) ? part[t - st] : 0;
        __syncthreads();
        part[t] += v;
        __syncthreads();
    }
    int ex = (t == 0) ? 0 : part[t - 1];
    for (int i = 0; i < 8; i++) {
        int o = ex + loc[i];
        offsets[base + i] = o;
        cursor[base + i] = o;
    }
    if (t == 1023) offsets[8192] = ex + s;
}

// ---- scatter edges into CSR-by-dst ----
__global__ void k_scatter(const int* __restrict__ srcI, const int* __restrict__ dstI,
                          const float* __restrict__ w, int* __restrict__ cursor,
                          int* __restrict__ src_s, float* __restrict__ w_s) {
    int e = blockIdx.x * 256 + threadIdx.x;
    if (e < E_N) {
        int dnode = dstI[e];
        int pos = atomicAdd(&cursor[dnode], 1);
        src_s[pos] = srcI[e];
        w_s[pos]  = w[e];
    }
}

// ---- Hp[ks] = A@W partial : pure-register, no LDS/barriers/atomics ----
// grid = 128 rb x 4 ks (512 blocks = 2/CU, one generation at 2 waves/EU).
// Wave = 16 rows x 128 cols. 64 phases of BK=32 per block.
// Pipeline: A depth-4 slots / B depth-2 slots, named registers only.
// Queue invariant at phase p (oldest->newest): A(p),A(p+1),B(p),A(p+2),B(p+1),A(p+3)
// so waiting on B(p) for the MFMAs drains A(p) but leaves A(p+2..) in flight.
__global__ void __launch_bounds__(256, 2) k_gemm(const float* __restrict__ A,
                                                 const unsigned short* __restrict__ Wp,
                                                 float* __restrict__ Hp) {
    const int rb   = blockIdx.x >> 2;     // 0..127
    const int ks   = blockIdx.x & 3;      // K slice of 2048
    const int tid  = threadIdx.x;
    const int w    = tid >> 6;
    const int lane = tid & 63;
    const int r16  = lane & 15;
    const int kg   = lane >> 4;           // 0..3

    const float* aP = A + (size_t)(rb * 64 + w * 16 + r16) * KDIM + ks * 2048 + kg * 8;
    const unsigned short* bP = Wp + (size_t)(ks * 64) * 4096 + r16 * 32 + kg * 8;

    f32x4 acc[8];
    f32x4 zero = {0.f, 0.f, 0.f, 0.f};
    #pragma unroll
    for (int t = 0; t < 8; t++) acc[t] = zero;

#define LDA(s0, s1, p)                                                  \
    do { const float* ap_ = aP + (size_t)(p) * 32;                      \
         s0 = *(const f32x4*)ap_; s1 = *(const f32x4*)(ap_ + 4); } while (0)
#define LDB(bb, p)                                                      \
    do { const b16x8* bp_ = (const b16x8*)(bP + (size_t)(p) * 4096);    \
         _Pragma("unroll")                                              \
         for (int t = 0; t < 8; t++) bb[t] = bp_[t * 64]; } while (0)
#define COMP(s0, s1, bb)                                                \
    do { union { b16x8 v; unsigned int u[4]; } af_;                     \
         af_.u[0] = cvtpk(s0[0], s0[1]);                                \
         af_.u[1] = cvtpk(s0[2], s0[3]);                                \
         af_.u[2] = cvtpk(s1[0], s1[1]);                                \
         af_.u[3] = cvtpk(s1[2], s1[3]);                                \
         _Pragma("unroll")                                              \
         for (int t = 0; t < 8; t++)                                    \
             acc[t] = __builtin_amdgcn_mfma_f32_16x16x32_bf16(af_.v, bb[t], acc[t], 0, 0, 0); \
    } while (0)
#define CL(p) ((p) < 64 ? (p) : 63)

    f32x4 a00, a01, a10, a11, a20, a21, a30, a31;
    b16x8 b0[8], b1[8];

    // prologue in queue order: A0 A1 B0 A2 B1 A3
    LDA(a00, a01, 0);
    LDA(a10, a11, 1);
    LDB(b0, 0);
    LDA(a20, a21, 2);
    LDB(b1, 1);
    LDA(a30, a31, 3);

    for (int p = 0; p < 64; p += 4) {
        COMP(a00, a01, b0); LDB(b0, CL(p + 2)); LDA(a00, a01, CL(p + 4));
        COMP(a10, a11, b1); LDB(b1, CL(p + 3)); LDA(a10, a11, CL(p + 5));
        COMP(a20, a21, b0); LDB(b0, CL(p + 4)); LDA(a20, a21, CL(p + 6));
        COMP(a30, a31, b1); LDB(b1, CL(p + 5)); LDA(a30, a31, CL(p + 7));
    }
#undef LDA
#undef LDB
#undef COMP
#undef CL

    // C/D map (16x16x32): col = r16 + t*16, row = kg*4 + j ; exclusive partial store
    float* hp = Hp + ((size_t)ks * V + (size_t)(rb * 64 + w * 16 + kg * 4)) * D + r16;
    #pragma unroll
    for (int t = 0; t < 8; t++)
        #pragma unroll
        for (int j = 0; j < 4; j++)
            hp[(size_t)j * D + t * 16] = acc[t][j];
}

// ---- H = b + Hp[0]+Hp[1]+Hp[2]+Hp[3] (f32x4) ----
__global__ void k_comb(const float* __restrict__ Hp, const float* __restrict__ b,
                       float* __restrict__ H) {
    int i = blockIdx.x * 256 + threadIdx.x;        // over V*D/4
    f32x4 bb = *(const f32x4*)(b + (i & 31) * 4);
    const f32x4* hp = (const f32x4*)Hp;
    const size_t q = (size_t)V * D / 4;
    f32x4 s = bb + hp[i] + hp[i + q] + hp[i + 2 * q] + hp[i + 3 * q];
    ((f32x4*)H)[i] = s;
}

// ---- emb = 0.8*P + 0.2*H, L2-normalize per row (V rows) ----
__global__ void k_emb(const float* __restrict__ H, const int* __restrict__ offsets,
                      const int* __restrict__ src_s, const float* __restrict__ w_s,
                      float* __restrict__ embn) {
    __shared__ float red[128];
    int v = blockIdx.x;
    int d = threadIdx.x;
    int s0 = offsets[v], s1 = offsets[v + 1];
    float acc = 0.f;
    for (int i = s0; i < s1; i++) {
        int s = src_s[i];
        float w = w_s[i];
        acc = fmaf(w, H[(size_t)s * D + d], acc);
    }
    float e = 0.8f * acc + 0.2f * H[(size_t)v * D + d];
    red[d] = e * e;
    __syncthreads();
    for (int st = 64; st > 0; st >>= 1) {
        if (d < st) red[d] += red[d + st];
        __syncthreads();
    }
    float norm = sqrtf(red[0]);
    float scale = 1.f / fmaxf(norm, 1e-12f);
    embn[(size_t)v * D + d] = e * scale;
}

// ---- out[n] = embn[x[n]] ----
__global__ void k_out(const int* __restrict__ x, const float* __restrict__ embn,
                      float* __restrict__ out) {
    int t = blockIdx.x * 256 + threadIdx.x;   // over NN * 32
    int n = t >> 5, c = t & 31;
    int xv = x[n];
    ((f32x4*)out)[t] = ((const f32x4*)embn)[xv * 32 + c];
}

extern "C" void kernel_launch(void* const* d_in, const int* in_sizes, int n_in,
                              void* d_out, int out_size, void* d_ws, size_t ws_size,
                              hipStream_t stream) {
    const int*   x      = (const int*)d_in[0];
    const int*   eSrc   = (const int*)d_in[1];          // edge_index[0]
    const int*   eDst   = ((const int*)d_in[1]) + E_N;  // edge_index[1]
    const float* eW     = (const float*)d_in[2];
    const float* A      = (const float*)d_in[3];        // embedding [V][V]
    const float* W      = (const float*)d_in[4];        // [V][D]
    const float* b      = (const float*)d_in[5];        // [D]
    float* out = (float*)d_out;

    char* ws = (char*)d_ws;
    unsigned short* Wp  = (unsigned short*)(ws);                        // 2 MB
    float* H            = (float*)(ws + (2u << 20));                    // 4 MB
    float* embn         = (float*)(ws + (6u << 20));                    // 4 MB
    float* Hp           = (float*)(ws + (10u << 20));                   // 16 MB (4 partials)
    int* offsets        = (int*)(ws + (26u << 20));                     // 8193 ints
    int* cursor         = (int*)(ws + (26u << 20) + 40960);             // 8192 ints (also hist)
    int* src_s          = (int*)(ws + (26u << 20) + 131072);            // 1 MB
    float* w_s          = (float*)(ws + (26u << 20) + 131072 + (1u << 20)); // 1 MB

    k_pack   <<<256, 256, 0, stream>>>(W, Wp, cursor);
    k_hist   <<<E_N / 256, 256, 0, stream>>>(eDst, cursor);
    k_scan   <<<1, 1024, 0, stream>>>(cursor, offsets, cursor);
    k_scatter<<<E_N / 256, 256, 0, stream>>>(eSrc, eDst, eW, cursor, src_s, w_s);
    k_gemm   <<<512, 256, 0, stream>>>(A, Wp, Hp);
    k_comb   <<<(V * D / 4) / 256, 256, 0, stream>>>(Hp, b, H);
    k_emb    <<<V, D, 0, stream>>>(H, offsets, src_s, w_s, embn);
    k_out    <<<(NN * 32) / 256, 256, 0, stream>>>(x, embn, out);
}

// Round 5
// 208.080 us; speedup vs baseline: 1.2901x; 1.0551x over previous
//
#include <hip/hip_runtime.h>
#include <hip/hip_bf16.h>

#define V     8192
#define E_N   262144
#define NN    262144
#define D     128
#define KDIM  8192
#define SPLITK 8

typedef __attribute__((ext_vector_type(8))) short b16x8;
typedef __attribute__((ext_vector_type(4))) float f32x4;

static __device__ __forceinline__ unsigned short f2bf(float f) {
    union { float f; unsigned int u; } v; v.f = f;
    unsigned int r = v.u + 0x7FFFu + ((v.u >> 16) & 1u);   // RNE
    return (unsigned short)(r >> 16);
}

static __device__ __forceinline__ unsigned int cvtpk(float lo, float hi) {
    unsigned int r;
    asm("v_cvt_pk_bf16_f32 %0, %1, %2" : "=v"(r) : "v"(lo), "v"(hi));
    return r;
}

// ---- W [K][D] fp32 -> Wp[kb][c][kk] bf16 (kb=k>>5, kk=k&31); also zero cursor ----
__global__ void k_pack(const float* __restrict__ W, unsigned short* __restrict__ Wp,
                       int* __restrict__ cursor) {
    __shared__ float tile[32][129];
    int kb = blockIdx.x;            // 0..255
    int t  = threadIdx.x;           // 0..255
    if (kb < 32) cursor[kb * 256 + t] = 0;
    #pragma unroll
    for (int i = 0; i < 16; i++) {
        int lin = i * 256 + t;      // over (kk,c)
        int kk = lin >> 7, c = lin & 127;
        tile[kk][c] = W[(size_t)(kb * 32 + kk) * D + c];
    }
    __syncthreads();
    unsigned short* outp = Wp + (size_t)kb * 4096;
    #pragma unroll
    for (int i = 0; i < 16; i++) {
        int o = i * 256 + t;        // over (c,kk)
        int c = o >> 5, kk = o & 31;
        outp[o] = f2bf(tile[kk][c]);
    }
}

// ---- degree histogram over dst ----
__global__ void k_hist(const int* __restrict__ dst, int* __restrict__ hist) {
    int e = blockIdx.x * 256 + threadIdx.x;
    if (e < E_N) atomicAdd(&hist[dst[e]], 1);
}

// ---- exclusive scan of 8192 counts, single block ----
__global__ void k_scan(const int* __restrict__ hist, int* __restrict__ offsets,
                       int* __restrict__ cursor) {
    __shared__ int part[1024];
    int t = threadIdx.x;
    int base = t * 8;
    int loc[8]; int s = 0;
    for (int i = 0; i < 8; i++) { loc[i] = s; s += hist[base + i]; }
    part[t] = s;
    __syncthreads();
    for (int st = 1; st < 1024; st <<= 1) {
        int v = (t >= st) ? part[t - st] : 0;
        __syncthreads();
        part[t] += v;
        __syncthreads();
    }
    int ex = (t == 0) ? 0 : part[t - 1];
    for (int i = 0; i < 8; i++) {
        int o = ex + loc[i];
        offsets[base + i] = o;
        cursor[base + i] = o;
    }
    if (t == 1023) offsets[8192] = ex + s;
}

// ---- scatter edges into CSR-by-dst ----
__global__ void k_scatter(const int* __restrict__ srcI, const int* __restrict__ dstI,
                          const float* __restrict__ w, int* __restrict__ cursor,
                          int* __restrict__ src_s, float* __restrict__ w_s) {
    int e = blockIdx.x * 256 + threadIdx.x;
    if (e < E_N) {
        int dnode = dstI[e];
        int pos = atomicAdd(&cursor[dnode], 1);
        src_s[pos] = srcI[e];
        w_s[pos]  = w[e];
    }
}

// ---- Hp[ks] = A@W partial : m97-style gl_lds double-buffered tile GEMM ----
// BM=64, BN=128, BK=32. grid = 128 rb x 8 ks = 1024 blocks (4/CU).
// 4 waves in 2Mx2N grid, each 32 rows x 64 cols (2 m-frags x 4 n-frags).
// A fp32 and B bf16 staged via global_load_lds(16B): linear LDS dest,
// XOR-pre-swizzled GLOBAL source, same-XOR ds_read (rule #21).
// One counted vmcnt(0) + raw s_barrier per K-step (T3 minimal 2-phase).
__global__ void __launch_bounds__(256, 4) k_gemm(const float* __restrict__ A,
                                                 const unsigned short* __restrict__ Wp,
                                                 float* __restrict__ Hp) {
    __shared__ float          As[2][64][32];    // [buf][row][k-float]; slot = 4 floats
    __shared__ unsigned short Bs[2][128][32];   // [buf][col][kk];      slot = 8 shorts

    const int rb  = blockIdx.x >> 3;
    const int ks  = blockIdx.x & 7;
    const int tid = threadIdx.x;
    const int w   = tid >> 6;
    const int l   = tid & 63;
    const int r16 = l & 15;
    const int kg  = l >> 4;           // 0..3
    const int wm  = w & 1, wn = w >> 1;

    // ---- staging sources (pre-swizzled) ----
    // A instr j covers rows w*16 + j*8 + l/8; lane slot = l&7; row&7 == (l>>3)&7
    const int aSwz = ((l & 7) ^ ((l >> 3) & 7)) * 4;          // float offset in 32-float row
    const float* aSrc0 = A + (size_t)(rb * 64 + w * 16 + (l >> 3)) * KDIM
                           + ks * 1024 + aSwz;
    const float* aSrc1 = aSrc0 + (size_t)8 * KDIM;
    // B instr j covers cols w*32 + j*16 + l/4; lane slot = l&3; (col>>1)&3 == (l>>3)&3
    const int bSwz = ((l & 3) ^ ((l >> 3) & 3)) * 8;          // short offset in 32-short col
    const unsigned short* bSrc0 = Wp + (size_t)(ks * 32) * 4096 + (w * 32 + (l >> 2)) * 32 + bSwz;
    const unsigned short* bSrc1 = bSrc0 + 16 * 32;

    f32x4 acc[2][4];
    f32x4 zero = {0.f, 0.f, 0.f, 0.f};
    #pragma unroll
    for (int m = 0; m < 2; m++)
        #pragma unroll
        for (int n = 0; n < 4; n++) acc[m][n] = zero;

#define STAGE(nb, t)                                                                     \
    do {                                                                                 \
        __builtin_amdgcn_global_load_lds(                                                \
            (const __attribute__((address_space(1))) void*)(aSrc0 + (size_t)(t) * 32),   \
            (__attribute__((address_space(3))) void*)&As[nb][w * 16][0], 16, 0, 0);      \
        __builtin_amdgcn_global_load_lds(                                                \
            (const __attribute__((address_space(1))) void*)(aSrc1 + (size_t)(t) * 32),   \
            (__attribute__((address_space(3))) void*)&As[nb][w * 16 + 8][0], 16, 0, 0);  \
        __builtin_amdgcn_global_load_lds(                                                \
            (const __attribute__((address_space(1))) void*)(bSrc0 + (size_t)(t) * 4096), \
            (__attribute__((address_space(3))) void*)&Bs[nb][w * 32][0], 16, 0, 0);      \
        __builtin_amdgcn_global_load_lds(                                                \
            (const __attribute__((address_space(1))) void*)(bSrc1 + (size_t)(t) * 4096), \
            (__attribute__((address_space(3))) void*)&Bs[nb][w * 32 + 16][0], 16, 0, 0); \
    } while (0)

#define COMPUTE(nb)                                                                      \
    do {                                                                                 \
        const float* abase = &As[nb][0][0];                                              \
        const unsigned short* bbase = &Bs[nb][0][0];                                     \
        const int s0 = (2 * kg) ^ (r16 & 7);                                             \
        const int s1 = (2 * kg + 1) ^ (r16 & 7);                                         \
        const int sb = kg ^ ((r16 >> 1) & 3);                                            \
        b16x8 bf[4];                                                                     \
        _Pragma("unroll")                                                                \
        for (int n = 0; n < 4; n++) {                                                    \
            int col = wn * 64 + n * 16 + r16;                                            \
            bf[n] = *(const b16x8*)(bbase + col * 32 + sb * 8);                          \
        }                                                                                \
        _Pragma("unroll")                                                                \
        for (int m = 0; m < 2; m++) {                                                    \
            int row = wm * 32 + m * 16 + r16;                                            \
            f32x4 a0 = *(const f32x4*)(abase + row * 32 + s0 * 4);                       \
            f32x4 a1 = *(const f32x4*)(abase + row * 32 + s1 * 4);                       \
            union { b16x8 v; unsigned int u[4]; } af;                                    \
            af.u[0] = cvtpk(a0[0], a0[1]);                                               \
            af.u[1] = cvtpk(a0[2], a0[3]);                                               \
            af.u[2] = cvtpk(a1[0], a1[1]);                                               \
            af.u[3] = cvtpk(a1[2], a1[3]);                                               \
            _Pragma("unroll")                                                            \
            for (int n = 0; n < 4; n++)                                                  \
                acc[m][n] = __builtin_amdgcn_mfma_f32_16x16x32_bf16(af.v, bf[n],         \
                                                                    acc[m][n], 0, 0, 0); \
        }                                                                                \
    } while (0)

    // prologue: tile 0 in flight
    STAGE(0, 0);
    asm volatile("s_waitcnt vmcnt(0)" ::: "memory");
    __builtin_amdgcn_s_barrier();

    int nb = 0;
    for (int t = 0; t < 31; ++t) {
        STAGE(nb ^ 1, t + 1);              // issue next tile
        COMPUTE(nb);                       // compute current (compiler inserts lgkmcnt)
        asm volatile("s_waitcnt vmcnt(0)" ::: "memory");
        __builtin_amdgcn_s_barrier();      // next tile landed; buf[nb] free to overwrite
        nb ^= 1;
    }
    COMPUTE(nb);                           // last tile, no prefetch
#undef STAGE
#undef COMPUTE

    // C/D map (16x16x32): col = r16, row = kg*4 + j ; exclusive partial store
    #pragma unroll
    for (int m = 0; m < 2; m++) {
        int row0 = rb * 64 + wm * 32 + m * 16 + kg * 4;
        #pragma unroll
        for (int n = 0; n < 4; n++) {
            int col = wn * 64 + n * 16 + r16;
            float* hp = Hp + ((size_t)ks * V + row0) * D + col;
            #pragma unroll
            for (int j = 0; j < 4; j++)
                hp[(size_t)j * D] = acc[m][n][j];
        }
    }
}

// ---- H = b + sum_{ks} Hp[ks] ----
__global__ void k_comb(const float* __restrict__ Hp, const float* __restrict__ b,
                       float* __restrict__ H) {
    int i = blockIdx.x * 256 + threadIdx.x;        // over V*D/4
    f32x4 s = *(const f32x4*)(b + (i & 31) * 4);
    const f32x4* hp = (const f32x4*)Hp;
    const size_t q = (size_t)V * D / 4;
    #pragma unroll
    for (int k = 0; k < SPLITK; k++) s += hp[i + k * q];
    ((f32x4*)H)[i] = s;
}

// ---- emb = 0.8*P + 0.2*H, L2-normalize per row (V rows) ----
__global__ void k_emb(const float* __restrict__ H, const int* __restrict__ offsets,
                      const int* __restrict__ src_s, const float* __restrict__ w_s,
                      float* __restrict__ embn) {
    __shared__ float red[128];
    int v = blockIdx.x;
    int d = threadIdx.x;
    int s0 = offsets[v], s1 = offsets[v + 1];
    float acc = 0.f;
    for (int i = s0; i < s1; i++) {
        int s = src_s[i];
        float w = w_s[i];
        acc = fmaf(w, H[(size_t)s * D + d], acc);
    }
    float e = 0.8f * acc + 0.2f * H[(size_t)v * D + d];
    red[d] = e * e;
    __syncthreads();
    for (int st = 64; st > 0; st >>= 1) {
        if (d < st) red[d] += red[d + st];
        __syncthreads();
    }
    float norm = sqrtf(red[0]);
    float scale = 1.f / fmaxf(norm, 1e-12f);
    embn[(size_t)v * D + d] = e * scale;
}

// ---- out[n] = embn[x[n]] ----
__global__ void k_out(const int* __restrict__ x, const float* __restrict__ embn,
                      float* __restrict__ out) {
    int t = blockIdx.x * 256 + threadIdx.x;   // over NN * 32
    int n = t >> 5, c = t & 31;
    int xv = x[n];
    ((f32x4*)out)[t] = ((const f32x4*)embn)[xv * 32 + c];
}

extern "C" void kernel_launch(void* const* d_in, const int* in_sizes, int n_in,
                              void* d_out, int out_size, void* d_ws, size_t ws_size,
                              hipStream_t stream) {
    const int*   x      = (const int*)d_in[0];
    const int*   eSrc   = (const int*)d_in[1];          // edge_index[0]
    const int*   eDst   = ((const int*)d_in[1]) + E_N;  // edge_index[1]
    const float* eW     = (const float*)d_in[2];
    const float* A      = (const float*)d_in[3];        // embedding [V][V]
    const float* W      = (const float*)d_in[4];        // [V][D]
    const float* b      = (const float*)d_in[5];        // [D]
    float* out = (float*)d_out;

    char* ws = (char*)d_ws;
    unsigned short* Wp  = (unsigned short*)(ws);                        // 2 MB
    float* H            = (float*)(ws + (2u << 20));                    // 4 MB
    float* embn         = (float*)(ws + (6u << 20));                    // 4 MB
    float* Hp           = (float*)(ws + (10u << 20));                   // 32 MB (8 partials)
    int* offsets        = (int*)(ws + (42u << 20));                     // 8193 ints
    int* cursor         = (int*)(ws + (42u << 20) + 40960);             // 8192 ints (also hist)
    int* src_s          = (int*)(ws + (42u << 20) + 131072);            // 1 MB
    float* w_s          = (float*)(ws + (42u << 20) + 131072 + (1u << 20)); // 1 MB

    k_pack   <<<256, 256, 0, stream>>>(W, Wp, cursor);
    k_hist   <<<E_N / 256, 256, 0, stream>>>(eDst, cursor);
    k_scan   <<<1, 1024, 0, stream>>>(cursor, offsets, cursor);
    k_scatter<<<E_N / 256, 256, 0, stream>>>(eSrc, eDst, eW, cursor, src_s, w_s);
    k_gemm   <<<1024, 256, 0, stream>>>(A, Wp, Hp);
    k_comb   <<<(V * D / 4) / 256, 256, 0, stream>>>(Hp, b, H);
    k_emb    <<<V, D, 0, stream>>>(H, offsets, src_s, w_s, embn);
    k_out    <<<(NN * 32) / 256, 256, 0, stream>>>(x, embn, out);
}